// Round 1
// 373.347 us; speedup vs baseline: 1.1236x; 1.1236x over previous
//
#include <hip/hip_runtime.h>

// ---------- fp32 <-> bf16 helpers ----------
__device__ __forceinline__ float bf2f(unsigned short u) {
    union { unsigned int i; float f; } v;
    v.i = ((unsigned int)u) << 16;
    return v.f;
}
__device__ __forceinline__ unsigned short f2bf(float f) {
    union { float f; unsigned int i; } v;
    v.f = f;
    unsigned int x = v.i;
    return (unsigned short)((x + 0x7fffu + ((x >> 16) & 1u)) >> 16);
}

typedef short bf16x8 __attribute__((ext_vector_type(8)));
typedef float f32x4 __attribute__((ext_vector_type(4)));

// ---------- prep: zero deg, x fp32->bf16, W panels -> bf16 (W1, W2, W3+W4) ----------
__global__ void prep_kernel(const float* __restrict__ x,
                            const float* __restrict__ W1, const float* __restrict__ W2,
                            const float* __restrict__ W3, const float* __restrict__ W4,
                            unsigned short* __restrict__ xb, unsigned short* __restrict__ Wb,
                            int* __restrict__ deg, int M, int nx4)
{
    int i = blockIdx.x * 256 + threadIdx.x;
    if (i < nx4) {
        float4 v = ((const float4*)x)[i];
        unsigned lo = (unsigned)f2bf(v.x) | ((unsigned)f2bf(v.y) << 16);
        unsigned hi = (unsigned)f2bf(v.z) | ((unsigned)f2bf(v.w) << 16);
        uint2 p; p.x = lo; p.y = hi;
        *(uint2*)(xb + (size_t)i * 4) = p;
    }
    if (i < M) deg[i] = 0;
    if (i < 16384) {
        Wb[i]         = f2bf(W1[i]);
        Wb[16384 + i] = f2bf(W2[i]);
        Wb[32768 + i] = f2bf(W3[i] + W4[i]);
    }
}

// ---------- CSR build ----------
__global__ void hist_kernel(const int* __restrict__ dst, int* __restrict__ deg, int ne) {
    int e = blockIdx.x * blockDim.x + threadIdx.x;
    if (e < ne) atomicAdd(&deg[dst[e]], 1);
}

// coalesced 3-stage scan (98 blocks x 1024)
__global__ __launch_bounds__(1024) void scan_local_kernel(
    const int* __restrict__ deg, int* __restrict__ offs, int* __restrict__ bsum, int n)
{
    __shared__ int sh[1024];
    int t = threadIdx.x;
    int i = blockIdx.x * 1024 + t;
    int v = (i < n) ? deg[i] : 0;
    sh[t] = v;
    __syncthreads();
    int acc = v;
    for (int off = 1; off < 1024; off <<= 1) {
        int y = (t >= off) ? sh[t - off] : 0;
        __syncthreads();
        acc += y;
        sh[t] = acc;
        __syncthreads();
    }
    if (i < n) offs[i] = acc - v;  // exclusive within block
    if (t == 1023) bsum[blockIdx.x] = acc;
}

__global__ __launch_bounds__(128) void scan_totals_kernel(
    int* __restrict__ bsum, int* __restrict__ offs, int nb, int n)
{
    __shared__ int sh[128];
    int t = threadIdx.x;
    int v = (t < nb) ? bsum[t] : 0;
    sh[t] = v;
    __syncthreads();
    int acc = v;
    for (int off = 1; off < 128; off <<= 1) {
        int y = (t >= off) ? sh[t - off] : 0;
        __syncthreads();
        acc += y;
        sh[t] = acc;
        __syncthreads();
    }
    if (t < nb) bsum[t] = acc - v;   // exclusive block offsets, in place
    if (t == 127) offs[n] = acc;     // grand total == NE
}

__global__ __launch_bounds__(1024) void scan_finalize_kernel(
    int* __restrict__ offs, const int* __restrict__ bsum, int* __restrict__ cursor, int n)
{
    int i = blockIdx.x * 1024 + threadIdx.x;
    if (i < n) {
        int o = offs[i] + bsum[i >> 10];
        offs[i] = o;
        cursor[i] = o;
    }
}

// XCD-range-partitioned CSR fill.
// Group r = blockIdx.x % 8 (round-robins onto XCD r) scans ALL edges but only
// commits edges with dst in [r*rangeSize, (r+1)*rangeSize). Each XCD's scattered
// 4B stores then stay within a ~0.8 MB csr slice + 50 KB cursor slice that fits
// resident in its 4 MB L2, so the ~16 writes per 64B line combine before one
// writeback (vs ~64B of HBM write traffic PER EDGE in the unpartitioned version).
// Correctness does not depend on the blockIdx->XCD mapping: every edge is taken
// by exactly one range group wherever it runs.
__global__ __launch_bounds__(256) void fill_csr_ranged_kernel(
    const int* __restrict__ src, const int* __restrict__ dst,
    int* __restrict__ cursor, int* __restrict__ csr, int ne, int rangeSize)
{
    const int r = blockIdx.x & 7;        // range / XCD id
    const int cb = blockIdx.x >> 3;      // chunk-block within the group
    const int nchunk = gridDim.x >> 3;
    const unsigned lo = (unsigned)(r * rangeSize);
    for (int e = cb * 256 + threadIdx.x; e < ne; e += nchunk * 256) {
        int d = dst[e];
        int s = src[e];                  // coalesced unconditional read
        if ((unsigned)(d - lo) < (unsigned)rangeSize) {
            int pos = atomicAdd(&cursor[d], 1);
            csr[pos] = s;
        }
    }
}

// ---------- gather: one wave per node, 8-deep masked unroll, bf16 out ----------
template<bool BF16SRC>
__global__ __launch_bounds__(256) void gather_kernel(
    const void* __restrict__ xsrc, const int* __restrict__ offs,
    const int* __restrict__ csr, unsigned short* __restrict__ gb, int M)
{
    const int wave = threadIdx.x >> 6;
    const int lane = threadIdx.x & 63;
    const int node = blockIdx.x * 4 + wave;
    if (node >= M) return;
    const int e0 = offs[node];
    const int e1 = offs[node + 1];

    float s0 = 0.f, s1 = 0.f, t0 = 0.f, t1 = 0.f;
    for (int e = e0; e < e1; e += 8) {
        int id[8];
        float m[8];
#pragma unroll
        for (int j = 0; j < 8; ++j) {
            int ee = e + j;
            bool ok = ee < e1;
            id[j] = csr[ok ? ee : e1 - 1];
            m[j] = ok ? 1.f : 0.f;
        }
#pragma unroll
        for (int j = 0; j < 8; ++j) {
            float lo, hi;
            if (BF16SRC) {
                unsigned v = *(const unsigned*)((const unsigned short*)xsrc +
                                                (size_t)id[j] * 128 + lane * 2);
                lo = bf2f((unsigned short)(v & 0xffffu));
                hi = bf2f((unsigned short)(v >> 16));
            } else {
                float2 v = *(const float2*)((const float*)xsrc +
                                            (size_t)id[j] * 128 + lane * 2);
                lo = v.x;
                hi = v.y;
            }
            if (j & 1) { t0 += m[j] * lo; t1 += m[j] * hi; }
            else       { s0 += m[j] * lo; s1 += m[j] * hi; }
        }
    }
    unsigned pk = (unsigned)f2bf(s0 + t0) | ((unsigned)f2bf(s1 + t1) << 16);
    *(unsigned*)(gb + (size_t)node * 128 + lane * 2) = pk;
}

// ---------- 3-panel bf16 MFMA GEMM + fp32 epilogue ----------
// P1 = x*W1^T ; P2 = g*W2^T ; P34 = g*(W3+W4)^T
// out = sigmoid(2*(P34 + d*(b3+b4))) * (2*(P2 + d*b2)) + P1 + b1
template<bool XBF16>
__global__ __launch_bounds__(256) void gemm_kernel(
    const void* __restrict__ xsrc, const unsigned short* __restrict__ gb,
    const int* __restrict__ deg, const unsigned short* __restrict__ Wb,
    const float* __restrict__ B1, const float* __restrict__ B2,
    const float* __restrict__ B3, const float* __restrict__ B4,
    float* __restrict__ out, int M)
{
    __shared__ unsigned short x_lds[64 * 136];
    __shared__ unsigned short g_lds[64 * 136];

    const int t = threadIdx.x;
    const int wave = t >> 6;
    const int lane = t & 63;
    const int ln = lane & 15;
    const int quad = lane >> 4;
    const int row0 = blockIdx.x * 64;

    // ---- stage x tile ----
    if (XBF16) {
        const unsigned short* xb = (const unsigned short*)xsrc;
#pragma unroll
        for (int i = 0; i < 4; ++i) {
            int c = i * 256 + t;          // 1024 chunks of 16B
            int row = c >> 4;
            int koff = (c & 15) * 8;
            int grow = row0 + row;
            if (grow > M - 1) grow = M - 1;
            *(uint4*)&x_lds[row * 136 + koff] =
                *(const uint4*)(xb + (size_t)grow * 128 + koff);
        }
    } else {
        const float* xf = (const float*)xsrc;
#pragma unroll
        for (int i = 0; i < 8; ++i) {
            int c = i * 256 + t;          // 2048 chunks of float4
            int row = c >> 5;
            int koff = (c & 31) * 4;
            int grow = row0 + row;
            if (grow > M - 1) grow = M - 1;
            float4 v = *(const float4*)(xf + (size_t)grow * 128 + koff);
            unsigned p0 = (unsigned)f2bf(v.x) | ((unsigned)f2bf(v.y) << 16);
            unsigned p1 = (unsigned)f2bf(v.z) | ((unsigned)f2bf(v.w) << 16);
            *(unsigned*)&x_lds[row * 136 + koff]     = p0;
            *(unsigned*)&x_lds[row * 136 + koff + 2] = p1;
        }
    }
    // ---- stage g tile ----
#pragma unroll
    for (int i = 0; i < 4; ++i) {
        int c = i * 256 + t;
        int row = c >> 4;
        int koff = (c & 15) * 8;
        int grow = row0 + row;
        if (grow > M - 1) grow = M - 1;
        *(uint4*)&g_lds[row * 136 + koff] =
            *(const uint4*)(gb + (size_t)grow * 128 + koff);
    }
    __syncthreads();

    // ---- 3-panel GEMM: wave owns cols [wave*32, wave*32+32) ----
    f32x4 acc[3][4][2];
#pragma unroll
    for (int p = 0; p < 3; ++p)
#pragma unroll
        for (int rt = 0; rt < 4; ++rt)
#pragma unroll
            for (int c = 0; c < 2; ++c) {
                acc[p][rt][c][0] = 0.f; acc[p][rt][c][1] = 0.f;
                acc[p][rt][c][2] = 0.f; acc[p][rt][c][3] = 0.f;
            }

#pragma unroll
    for (int kk = 0; kk < 4; ++kk) {
        bf16x8 ax[4], ag[4];
#pragma unroll
        for (int rt = 0; rt < 4; ++rt) {
            ax[rt] = *(const bf16x8*)&x_lds[(rt * 16 + ln) * 136 + kk * 32 + quad * 8];
            ag[rt] = *(const bf16x8*)&g_lds[(rt * 16 + ln) * 136 + kk * 32 + quad * 8];
        }
#pragma unroll
        for (int p = 0; p < 3; ++p) {
#pragma unroll
            for (int c = 0; c < 2; ++c) {
                int col = wave * 32 + c * 16 + ln;
                bf16x8 bw = *(const bf16x8*)(Wb + (size_t)p * 16384 +
                                             (size_t)col * 128 + kk * 32 + quad * 8);
#pragma unroll
                for (int rt = 0; rt < 4; ++rt) {
                    acc[p][rt][c] = __builtin_amdgcn_mfma_f32_16x16x32_bf16(
                        (p == 0) ? ax[rt] : ag[rt], bw, acc[p][rt][c], 0, 0, 0);
                }
            }
        }
    }

    // ---- epilogue (fp32) ----
#pragma unroll
    for (int rt = 0; rt < 4; ++rt) {
#pragma unroll
        for (int i = 0; i < 4; ++i) {
            int row = row0 + rt * 16 + quad * 4 + i;
            if (row < M) {
                float dg = (float)deg[row];
#pragma unroll
                for (int c = 0; c < 2; ++c) {
                    int col = wave * 32 + c * 16 + ln;
                    float p1 = acc[0][rt][c][i] + B1[col];
                    float h2 = 2.f * (acc[1][rt][c][i] + dg * B2[col]);
                    float z  = 2.f * (acc[2][rt][c][i] + dg * (B3[col] + B4[col]));
                    float g = 1.f / (1.f + __expf(-z));
                    out[(size_t)row * 128 + col] = g * h2 + p1;
                }
            }
        }
    }
}

extern "C" void kernel_launch(void* const* d_in, const int* in_sizes, int n_in,
                              void* d_out, int out_size, void* d_ws, size_t ws_size,
                              hipStream_t stream) {
    const float* x  = (const float*)d_in[0];
    const int* eidx = (const int*)d_in[1];
    const float* W1 = (const float*)d_in[2];
    const float* B1 = (const float*)d_in[3];
    const float* W2 = (const float*)d_in[4];
    const float* B2 = (const float*)d_in[5];
    const float* W3 = (const float*)d_in[6];
    const float* B3 = (const float*)d_in[7];
    const float* W4 = (const float*)d_in[8];
    const float* B4 = (const float*)d_in[9];
    float* out      = (float*)d_out;

    const int M  = in_sizes[0] / 128;   // 100000 nodes
    const int NE = in_sizes[1] / 2;     // 1600000 edges
    const int* src = eidx;
    const int* dst = eidx + NE;

    // workspace needs: full path uses xb (bf16 copy of x); fallback gathers fp32 x.
    const size_t xb_bytes = (size_t)M * 128 * 2;
    const size_t fixed =
        (((size_t)M * 128 * 2 + 127) & ~(size_t)127) +     // gb
        (((size_t)3 * 16384 * 2 + 127) & ~(size_t)127) +   // Wb
        3 * (((size_t)(M + 1) * 4 + 127) & ~(size_t)127) + // deg, offs, cursor
        256 * 4 +                                          // bsum
        (((size_t)NE * 4 + 127) & ~(size_t)127);           // csr
    const bool full = ws_size >= fixed + xb_bytes + 1024;

    char* ws = (char*)d_ws;
    size_t off = 0;
    auto take = [&](size_t bytes) -> char* {
        char* p = ws + off;
        off = (off + bytes + 127) & ~(size_t)127;
        return p;
    };
    unsigned short* xb = full ? (unsigned short*)take(xb_bytes) : nullptr;
    unsigned short* gb = (unsigned short*)take((size_t)M * 128 * 2);
    unsigned short* Wb = (unsigned short*)take(3 * 16384 * 2);
    int* deg    = (int*)take((size_t)M * 4);
    int* offs   = (int*)take((size_t)(M + 1) * 4);
    int* cursor = (int*)take((size_t)M * 4);
    int* bsum   = (int*)take(256 * 4);
    int* csr    = (int*)take((size_t)NE * 4);

    const int nx4 = full ? (M * 128 / 4) : 0;
    const int prep_elems = full ? (M * 32) : (M > 16384 ? M : 16384);
    const int nbScan = (M + 1023) / 1024;
    const int rangeSize = (M + 7) / 8;

    prep_kernel<<<(prep_elems + 255) / 256, 256, 0, stream>>>(
        x, W1, W2, W3, W4, full ? xb : gb, Wb, deg, M, nx4);
    hist_kernel<<<(NE + 255) / 256, 256, 0, stream>>>(dst, deg, NE);
    scan_local_kernel<<<nbScan, 1024, 0, stream>>>(deg, offs, bsum, M);
    scan_totals_kernel<<<1, 128, 0, stream>>>(bsum, offs, nbScan, M);
    scan_finalize_kernel<<<nbScan, 1024, 0, stream>>>(offs, bsum, cursor, M);
    // 8 range-groups x 256 chunk-blocks; group r lands on XCD r via round-robin.
    fill_csr_ranged_kernel<<<2048, 256, 0, stream>>>(src, dst, cursor, csr, NE, rangeSize);
    if (full) {
        gather_kernel<true><<<(M + 3) / 4, 256, 0, stream>>>(xb, offs, csr, gb, M);
        gemm_kernel<true><<<(M + 63) / 64, 256, 0, stream>>>(
            xb, gb, deg, Wb, B1, B2, B3, B4, out, M);
    } else {
        gather_kernel<false><<<(M + 3) / 4, 256, 0, stream>>>(x, offs, csr, gb, M);
        gemm_kernel<false><<<(M + 63) / 64, 256, 0, stream>>>(
            x, gb, deg, Wb, B1, B2, B3, B4, out, M);
    }
}

// Round 2
// 345.027 us; speedup vs baseline: 1.2158x; 1.0821x over previous
//
#include <hip/hip_runtime.h>

// ---------- fp32 <-> bf16 helpers ----------
__device__ __forceinline__ float bf2f(unsigned short u) {
    union { unsigned int i; float f; } v;
    v.i = ((unsigned int)u) << 16;
    return v.f;
}
__device__ __forceinline__ unsigned short f2bf(float f) {
    union { float f; unsigned int i; } v;
    v.f = f;
    unsigned int x = v.i;
    return (unsigned short)((x + 0x7fffu + ((x >> 16) & 1u)) >> 16);
}

typedef short bf16x8 __attribute__((ext_vector_type(8)));
typedef float f32x4 __attribute__((ext_vector_type(4)));

// ---------- prep: zero deg, x fp32->bf16, W panels -> bf16 (W1, W2, W3+W4) ----------
__global__ void prep_kernel(const float* __restrict__ x,
                            const float* __restrict__ W1, const float* __restrict__ W2,
                            const float* __restrict__ W3, const float* __restrict__ W4,
                            unsigned short* __restrict__ xb, unsigned short* __restrict__ Wb,
                            int* __restrict__ deg, int M, int nx4)
{
    int i = blockIdx.x * 256 + threadIdx.x;
    if (i < nx4) {
        float4 v = ((const float4*)x)[i];
        unsigned lo = (unsigned)f2bf(v.x) | ((unsigned)f2bf(v.y) << 16);
        unsigned hi = (unsigned)f2bf(v.z) | ((unsigned)f2bf(v.w) << 16);
        uint2 p; p.x = lo; p.y = hi;
        *(uint2*)(xb + (size_t)i * 4) = p;
    }
    if (i < M) deg[i] = 0;
    if (i < 16384) {
        Wb[i]         = f2bf(W1[i]);
        Wb[16384 + i] = f2bf(W2[i]);
        Wb[32768 + i] = f2bf(W3[i] + W4[i]);
    }
}

// ---------- CSR build ----------
// hist + rank capture: the atomicAdd we already pay for ALSO yields each edge's
// stable rank among same-dst edges. Pack (rank<<17)|dst (dst < 2^17; rank << 2^15
// at mean degree 16) into a sequential 4B/edge array -> the fill pass needs NO atomics.
__global__ void hist_rank_kernel(const int* __restrict__ dst, int* __restrict__ deg,
                                 unsigned* __restrict__ rankdst, int ne) {
    int e = blockIdx.x * blockDim.x + threadIdx.x;
    if (e < ne) {
        int d = __builtin_nontemporal_load(&dst[e]);
        int r = atomicAdd(&deg[d], 1);
        rankdst[e] = ((unsigned)r << 17) | (unsigned)d;
    }
}

// plain hist for the low-workspace fallback path
__global__ void hist_kernel(const int* __restrict__ dst, int* __restrict__ deg, int ne) {
    int e = blockIdx.x * blockDim.x + threadIdx.x;
    if (e < ne) atomicAdd(&deg[dst[e]], 1);
}

// coalesced 3-stage scan (98 blocks x 1024)
__global__ __launch_bounds__(1024) void scan_local_kernel(
    const int* __restrict__ deg, int* __restrict__ offs, int* __restrict__ bsum, int n)
{
    __shared__ int sh[1024];
    int t = threadIdx.x;
    int i = blockIdx.x * 1024 + t;
    int v = (i < n) ? deg[i] : 0;
    sh[t] = v;
    __syncthreads();
    int acc = v;
    for (int off = 1; off < 1024; off <<= 1) {
        int y = (t >= off) ? sh[t - off] : 0;
        __syncthreads();
        acc += y;
        sh[t] = acc;
        __syncthreads();
    }
    if (i < n) offs[i] = acc - v;  // exclusive within block
    if (t == 1023) bsum[blockIdx.x] = acc;
}

__global__ __launch_bounds__(128) void scan_totals_kernel(
    int* __restrict__ bsum, int* __restrict__ offs, int nb, int n)
{
    __shared__ int sh[128];
    int t = threadIdx.x;
    int v = (t < nb) ? bsum[t] : 0;
    sh[t] = v;
    __syncthreads();
    int acc = v;
    for (int off = 1; off < 128; off <<= 1) {
        int y = (t >= off) ? sh[t - off] : 0;
        __syncthreads();
        acc += y;
        sh[t] = acc;
        __syncthreads();
    }
    if (t < nb) bsum[t] = acc - v;   // exclusive block offsets, in place
    if (t == 127) offs[n] = acc;     // grand total == NE
}

// cursor may be null (atomic-free fill path does not need it)
__global__ __launch_bounds__(1024) void scan_finalize_kernel(
    int* __restrict__ offs, const int* __restrict__ bsum, int* __restrict__ cursor, int n)
{
    int i = blockIdx.x * 1024 + threadIdx.x;
    if (i < n) {
        int o = offs[i] + bsum[i >> 10];
        offs[i] = o;
        if (cursor) cursor[i] = o;
    }
}

// Atomic-free, XCD-range-partitioned CSR fill.
// Group r = blockIdx.x % 8 (round-robins onto XCD r) scans all edges with
// NON-TEMPORAL loads (so the 12.8 MB/group edge stream does not evict the dirty
// csr lines from that XCD's 4 MB L2) and commits only edges whose dst falls in
// its 1/8 node range: pos = offs[d] + rank, plain store. The ~0.8 MB csr slice
// + 50 KB offs slice stay L2-resident, so ~16 writes/line combine before one
// 64B writeback (vs ~45 B/edge of HBM write traffic when the stream polluted L2).
__global__ __launch_bounds__(256) void fill_csr_pos_kernel(
    const int* __restrict__ src, const unsigned* __restrict__ rankdst,
    const int* __restrict__ offs, int* __restrict__ csr, int ne, int rangeSize)
{
    const int r = blockIdx.x & 7;        // range / XCD id
    const int cb = blockIdx.x >> 3;      // chunk-block within the group
    const int nchunk = gridDim.x >> 3;
    const unsigned lo = (unsigned)(r * rangeSize);
    for (int e = cb * 256 + threadIdx.x; e < ne; e += nchunk * 256) {
        unsigned rd = __builtin_nontemporal_load(&rankdst[e]);
        int s = __builtin_nontemporal_load(&src[e]);   // coalesced unconditional read
        unsigned d = rd & 0x1FFFFu;
        if (d - lo < (unsigned)rangeSize) {
            int pos = offs[d] + (int)(rd >> 17);
            csr[pos] = s;
        }
    }
}

// fallback (low workspace): atomic-cursor ranged fill
__global__ __launch_bounds__(256) void fill_csr_ranged_kernel(
    const int* __restrict__ src, const int* __restrict__ dst,
    int* __restrict__ cursor, int* __restrict__ csr, int ne, int rangeSize)
{
    const int r = blockIdx.x & 7;
    const int cb = blockIdx.x >> 3;
    const int nchunk = gridDim.x >> 3;
    const unsigned lo = (unsigned)(r * rangeSize);
    for (int e = cb * 256 + threadIdx.x; e < ne; e += nchunk * 256) {
        int d = dst[e];
        int s = src[e];
        if ((unsigned)(d - lo) < (unsigned)rangeSize) {
            int pos = atomicAdd(&cursor[d], 1);
            csr[pos] = s;
        }
    }
}

// ---------- gather: one wave per node, 8-deep masked unroll, bf16 out ----------
template<bool BF16SRC>
__global__ __launch_bounds__(256) void gather_kernel(
    const void* __restrict__ xsrc, const int* __restrict__ offs,
    const int* __restrict__ csr, unsigned short* __restrict__ gb, int M)
{
    const int wave = threadIdx.x >> 6;
    const int lane = threadIdx.x & 63;
    const int node = blockIdx.x * 4 + wave;
    if (node >= M) return;
    const int e0 = offs[node];
    const int e1 = offs[node + 1];

    float s0 = 0.f, s1 = 0.f, t0 = 0.f, t1 = 0.f;
    for (int e = e0; e < e1; e += 8) {
        int id[8];
        float m[8];
#pragma unroll
        for (int j = 0; j < 8; ++j) {
            int ee = e + j;
            bool ok = ee < e1;
            id[j] = csr[ok ? ee : e1 - 1];
            m[j] = ok ? 1.f : 0.f;
        }
#pragma unroll
        for (int j = 0; j < 8; ++j) {
            float lo, hi;
            if (BF16SRC) {
                unsigned v = *(const unsigned*)((const unsigned short*)xsrc +
                                                (size_t)id[j] * 128 + lane * 2);
                lo = bf2f((unsigned short)(v & 0xffffu));
                hi = bf2f((unsigned short)(v >> 16));
            } else {
                float2 v = *(const float2*)((const float*)xsrc +
                                            (size_t)id[j] * 128 + lane * 2);
                lo = v.x;
                hi = v.y;
            }
            if (j & 1) { t0 += m[j] * lo; t1 += m[j] * hi; }
            else       { s0 += m[j] * lo; s1 += m[j] * hi; }
        }
    }
    unsigned pk = (unsigned)f2bf(s0 + t0) | ((unsigned)f2bf(s1 + t1) << 16);
    *(unsigned*)(gb + (size_t)node * 128 + lane * 2) = pk;
}

// ---------- 3-panel bf16 MFMA GEMM + fp32 epilogue ----------
// P1 = x*W1^T ; P2 = g*W2^T ; P34 = g*(W3+W4)^T
// out = sigmoid(2*(P34 + d*(b3+b4))) * (2*(P2 + d*b2)) + P1 + b1
template<bool XBF16>
__global__ __launch_bounds__(256) void gemm_kernel(
    const void* __restrict__ xsrc, const unsigned short* __restrict__ gb,
    const int* __restrict__ deg, const unsigned short* __restrict__ Wb,
    const float* __restrict__ B1, const float* __restrict__ B2,
    const float* __restrict__ B3, const float* __restrict__ B4,
    float* __restrict__ out, int M)
{
    __shared__ unsigned short x_lds[64 * 136];
    __shared__ unsigned short g_lds[64 * 136];

    const int t = threadIdx.x;
    const int wave = t >> 6;
    const int lane = t & 63;
    const int ln = lane & 15;
    const int quad = lane >> 4;
    const int row0 = blockIdx.x * 64;

    // ---- stage x tile ----
    if (XBF16) {
        const unsigned short* xb = (const unsigned short*)xsrc;
#pragma unroll
        for (int i = 0; i < 4; ++i) {
            int c = i * 256 + t;          // 1024 chunks of 16B
            int row = c >> 4;
            int koff = (c & 15) * 8;
            int grow = row0 + row;
            if (grow > M - 1) grow = M - 1;
            *(uint4*)&x_lds[row * 136 + koff] =
                *(const uint4*)(xb + (size_t)grow * 128 + koff);
        }
    } else {
        const float* xf = (const float*)xsrc;
#pragma unroll
        for (int i = 0; i < 8; ++i) {
            int c = i * 256 + t;          // 2048 chunks of float4
            int row = c >> 5;
            int koff = (c & 31) * 4;
            int grow = row0 + row;
            if (grow > M - 1) grow = M - 1;
            float4 v = *(const float4*)(xf + (size_t)grow * 128 + koff);
            unsigned p0 = (unsigned)f2bf(v.x) | ((unsigned)f2bf(v.y) << 16);
            unsigned p1 = (unsigned)f2bf(v.z) | ((unsigned)f2bf(v.w) << 16);
            *(unsigned*)&x_lds[row * 136 + koff]     = p0;
            *(unsigned*)&x_lds[row * 136 + koff + 2] = p1;
        }
    }
    // ---- stage g tile ----
#pragma unroll
    for (int i = 0; i < 4; ++i) {
        int c = i * 256 + t;
        int row = c >> 4;
        int koff = (c & 15) * 8;
        int grow = row0 + row;
        if (grow > M - 1) grow = M - 1;
        *(uint4*)&g_lds[row * 136 + koff] =
            *(const uint4*)(gb + (size_t)grow * 128 + koff);
    }
    __syncthreads();

    // ---- 3-panel GEMM: wave owns cols [wave*32, wave*32+32) ----
    f32x4 acc[3][4][2];
#pragma unroll
    for (int p = 0; p < 3; ++p)
#pragma unroll
        for (int rt = 0; rt < 4; ++rt)
#pragma unroll
            for (int c = 0; c < 2; ++c) {
                acc[p][rt][c][0] = 0.f; acc[p][rt][c][1] = 0.f;
                acc[p][rt][c][2] = 0.f; acc[p][rt][c][3] = 0.f;
            }

#pragma unroll
    for (int kk = 0; kk < 4; ++kk) {
        bf16x8 ax[4], ag[4];
#pragma unroll
        for (int rt = 0; rt < 4; ++rt) {
            ax[rt] = *(const bf16x8*)&x_lds[(rt * 16 + ln) * 136 + kk * 32 + quad * 8];
            ag[rt] = *(const bf16x8*)&g_lds[(rt * 16 + ln) * 136 + kk * 32 + quad * 8];
        }
#pragma unroll
        for (int p = 0; p < 3; ++p) {
#pragma unroll
            for (int c = 0; c < 2; ++c) {
                int col = wave * 32 + c * 16 + ln;
                bf16x8 bw = *(const bf16x8*)(Wb + (size_t)p * 16384 +
                                             (size_t)col * 128 + kk * 32 + quad * 8);
#pragma unroll
                for (int rt = 0; rt < 4; ++rt) {
                    acc[p][rt][c] = __builtin_amdgcn_mfma_f32_16x16x32_bf16(
                        (p == 0) ? ax[rt] : ag[rt], bw, acc[p][rt][c], 0, 0, 0);
                }
            }
        }
    }

    // ---- epilogue (fp32) ----
#pragma unroll
    for (int rt = 0; rt < 4; ++rt) {
#pragma unroll
        for (int i = 0; i < 4; ++i) {
            int row = row0 + rt * 16 + quad * 4 + i;
            if (row < M) {
                float dg = (float)deg[row];
#pragma unroll
                for (int c = 0; c < 2; ++c) {
                    int col = wave * 32 + c * 16 + ln;
                    float p1 = acc[0][rt][c][i] + B1[col];
                    float h2 = 2.f * (acc[1][rt][c][i] + dg * B2[col]);
                    float z  = 2.f * (acc[2][rt][c][i] + dg * (B3[col] + B4[col]));
                    float g = 1.f / (1.f + __expf(-z));
                    out[(size_t)row * 128 + col] = g * h2 + p1;
                }
            }
        }
    }
}

extern "C" void kernel_launch(void* const* d_in, const int* in_sizes, int n_in,
                              void* d_out, int out_size, void* d_ws, size_t ws_size,
                              hipStream_t stream) {
    const float* x  = (const float*)d_in[0];
    const int* eidx = (const int*)d_in[1];
    const float* W1 = (const float*)d_in[2];
    const float* B1 = (const float*)d_in[3];
    const float* W2 = (const float*)d_in[4];
    const float* B2 = (const float*)d_in[5];
    const float* W3 = (const float*)d_in[6];
    const float* B3 = (const float*)d_in[7];
    const float* W4 = (const float*)d_in[8];
    const float* B4 = (const float*)d_in[9];
    float* out      = (float*)d_out;

    const int M  = in_sizes[0] / 128;   // 100000 nodes
    const int NE = in_sizes[1] / 2;     // 1600000 edges
    const int* src = eidx;
    const int* dst = eidx + NE;

    auto pad = [](size_t b) { return (b + 127) & ~(size_t)127; };
    const size_t xb_bytes  = pad((size_t)M * 128 * 2);
    const size_t gb_bytes  = pad((size_t)M * 128 * 2);
    const size_t wb_bytes  = pad((size_t)3 * 16384 * 2);
    const size_t nd_bytes  = pad((size_t)(M + 1) * 4);
    const size_t csr_bytes = pad((size_t)NE * 4);
    const size_t rk_bytes  = pad((size_t)NE * 4);

    // full path: xb (bf16 x) + rankdst (atomic-free fill)
    const size_t need_full =
        xb_bytes + gb_bytes + wb_bytes + 2 * nd_bytes + 256 * 4 + csr_bytes + rk_bytes;
    const bool full = ws_size >= need_full + 1024;

    char* ws = (char*)d_ws;
    size_t off = 0;
    auto take = [&](size_t bytes) -> char* {
        char* p = ws + off;
        off = (off + bytes + 127) & ~(size_t)127;
        return p;
    };

    const int nbScan = (M + 1023) / 1024;
    const int rangeSize = (M + 7) / 8;

    if (full) {
        unsigned short* xb = (unsigned short*)take(xb_bytes);
        unsigned short* gb = (unsigned short*)take(gb_bytes);
        unsigned short* Wb = (unsigned short*)take(wb_bytes);
        int* deg      = (int*)take((size_t)M * 4);
        int* offs     = (int*)take((size_t)(M + 1) * 4);
        int* bsum     = (int*)take(256 * 4);
        int* csr      = (int*)take((size_t)NE * 4);
        unsigned* rkd = (unsigned*)take((size_t)NE * 4);

        const int nx4 = M * 128 / 4;
        prep_kernel<<<(M * 32 + 255) / 256, 256, 0, stream>>>(
            x, W1, W2, W3, W4, xb, Wb, deg, M, nx4);
        hist_rank_kernel<<<(NE + 255) / 256, 256, 0, stream>>>(dst, deg, rkd, NE);
        scan_local_kernel<<<nbScan, 1024, 0, stream>>>(deg, offs, bsum, M);
        scan_totals_kernel<<<1, 128, 0, stream>>>(bsum, offs, nbScan, M);
        scan_finalize_kernel<<<nbScan, 1024, 0, stream>>>(offs, bsum, nullptr, M);
        fill_csr_pos_kernel<<<2048, 256, 0, stream>>>(src, rkd, offs, csr, NE, rangeSize);
        gather_kernel<true><<<(M + 3) / 4, 256, 0, stream>>>(xb, offs, csr, gb, M);
        gemm_kernel<true><<<(M + 63) / 64, 256, 0, stream>>>(
            xb, gb, deg, Wb, B1, B2, B3, B4, out, M);
    } else {
        // low-workspace fallback: fp32 gather + atomic-cursor fill
        unsigned short* gb = (unsigned short*)take(gb_bytes);
        unsigned short* Wb = (unsigned short*)take(wb_bytes);
        int* deg    = (int*)take((size_t)M * 4);
        int* offs   = (int*)take((size_t)(M + 1) * 4);
        int* cursor = (int*)take((size_t)M * 4);
        int* bsum   = (int*)take(256 * 4);
        int* csr    = (int*)take((size_t)NE * 4);

        const int prep_elems = (M > 16384 ? M : 16384);
        prep_kernel<<<(prep_elems + 255) / 256, 256, 0, stream>>>(
            x, W1, W2, W3, W4, gb, Wb, deg, M, 0);
        hist_kernel<<<(NE + 255) / 256, 256, 0, stream>>>(dst, deg, NE);
        scan_local_kernel<<<nbScan, 1024, 0, stream>>>(deg, offs, bsum, M);
        scan_totals_kernel<<<1, 128, 0, stream>>>(bsum, offs, nbScan, M);
        scan_finalize_kernel<<<nbScan, 1024, 0, stream>>>(offs, bsum, cursor, M);
        fill_csr_ranged_kernel<<<2048, 256, 0, stream>>>(src, dst, cursor, csr, NE, rangeSize);
        gather_kernel<false><<<(M + 3) / 4, 256, 0, stream>>>(x, offs, csr, gb, M);
        gemm_kernel<false><<<(M + 63) / 64, 256, 0, stream>>>(
            x, gb, deg, Wb, B1, B2, B3, B4, out, M);
    }
}

// Round 3
// 288.249 us; speedup vs baseline: 1.4553x; 1.1970x over previous
//
#include <hip/hip_runtime.h>

// ---------- fp32 <-> bf16 helpers ----------
__device__ __forceinline__ float bf2f(unsigned short u) {
    union { unsigned int i; float f; } v;
    v.i = ((unsigned int)u) << 16;
    return v.f;
}
__device__ __forceinline__ unsigned short f2bf(float f) {
    union { float f; unsigned int i; } v;
    v.f = f;
    unsigned int x = v.i;
    return (unsigned short)((x + 0x7fffu + ((x >> 16) & 1u)) >> 16);
}

typedef short bf16x8 __attribute__((ext_vector_type(8)));
typedef float f32x4 __attribute__((ext_vector_type(4)));

// bucket geometry: 512 nodes per bucket (shift 9); NB = ceil(M/512) <= 256
#define BSHIFT 9
#define BRANGE 512

// ---------- prep: zero deg+bcnt, x fp32->bf16, W panels -> bf16 ----------
__global__ void prep_kernel(const float* __restrict__ x,
                            const float* __restrict__ W1, const float* __restrict__ W2,
                            const float* __restrict__ W3, const float* __restrict__ W4,
                            unsigned short* __restrict__ xb, unsigned short* __restrict__ Wb,
                            int* __restrict__ deg, int* __restrict__ bcnt, int M, int nx4)
{
    int i = blockIdx.x * 256 + threadIdx.x;
    if (i < nx4) {
        float4 v = ((const float4*)x)[i];
        unsigned lo = (unsigned)f2bf(v.x) | ((unsigned)f2bf(v.y) << 16);
        unsigned hi = (unsigned)f2bf(v.z) | ((unsigned)f2bf(v.w) << 16);
        uint2 p; p.x = lo; p.y = hi;
        *(uint2*)(xb + (size_t)i * 4) = p;
    }
    if (i < M) deg[i] = 0;
    if (bcnt && i < 256) bcnt[i] = 0;
    if (i < 16384) {
        Wb[i]         = f2bf(W1[i]);
        Wb[16384 + i] = f2bf(W2[i]);
        Wb[32768 + i] = f2bf(W3[i] + W4[i]);
    }
}

// ---------- bucketed CSR build (atomic-poor) ----------
// Exact per-bucket edge counts: LDS-privatized 196-bin histogram.
// Global atomics: 256 blocks x <=NB bins ~= 50k (vs 1.6M per-edge).
__global__ __launch_bounds__(512) void bucket_hist_kernel(
    const int* __restrict__ dst, int* __restrict__ bcnt, int ne, int nb)
{
    __shared__ int h[256];
    int t = threadIdx.x;
    if (t < 256) h[t] = 0;
    __syncthreads();
    for (int i = blockIdx.x * 512 + t; i < ne; i += gridDim.x * 512)
        atomicAdd(&h[dst[i] >> BSHIFT], 1);
    __syncthreads();
    if (t < nb) {
        int c = h[t];
        if (c) atomicAdd(&bcnt[t], c);
    }
}

// single-block scan of bucket counts -> boff[0..nb] and region cursors gcur
__global__ __launch_bounds__(256) void bucket_scan_kernel(
    const int* __restrict__ bcnt, int* __restrict__ boff, int* __restrict__ gcur, int nb)
{
    __shared__ int sh[256];
    int t = threadIdx.x;
    int v = (t < nb) ? bcnt[t] : 0;
    sh[t] = v;
    __syncthreads();
    int acc = v;
    for (int off = 1; off < 256; off <<= 1) {
        int y = (t >= off) ? sh[t - off] : 0;
        __syncthreads();
        acc += y;
        sh[t] = acc;
        __syncthreads();
    }
    if (t < nb) {
        boff[t + 1] = acc;        // inclusive
        gcur[t] = acc - v;        // exclusive: region cursor
    }
    if (t == 0) boff[0] = 0;
}

// Partition edges into dst-range buckets. Per block: LDS count pass, ONE global
// atomic per touched bucket to claim a contiguous run (~32 entries = 256B), then
// LDS-cursor scatter. Writes are short coalesced runs; no per-edge atomics.
__global__ __launch_bounds__(512) void bucketize_kernel(
    const int* __restrict__ src, const int* __restrict__ dst,
    int* __restrict__ gcur, int2* __restrict__ bucketed, int ne, int chunk)
{
    __shared__ int cnt[256];
    __shared__ int sbase[256];
    const int t = threadIdx.x;
    const int e0 = blockIdx.x * chunk;
    const int e1 = (e0 + chunk < ne) ? e0 + chunk : ne;

    if (t < 256) cnt[t] = 0;
    __syncthreads();
    for (int e = e0 + t; e < e1; e += 512)
        atomicAdd(&cnt[dst[e] >> BSHIFT], 1);
    __syncthreads();
    if (t < 256) {
        int c = cnt[t];
        sbase[t] = c ? atomicAdd(&gcur[t], c) : 0;
        cnt[t] = 0;
    }
    __syncthreads();
    for (int e = e0 + t; e < e1; e += 512) {
        int d = dst[e];
        int b = d >> BSHIFT;
        int loc = atomicAdd(&cnt[b], 1);
        int2 v; v.x = src[e]; v.y = d;
        bucketed[sbase[b] + loc] = v;
    }
}

// one block per bucket: LDS histogram over the bucket's 512-node range -> deg (plain stores)
__global__ __launch_bounds__(512) void bucket_count_kernel(
    const int2* __restrict__ bucketed, const int* __restrict__ boff,
    int* __restrict__ deg, int M)
{
    __shared__ int cnt[BRANGE];
    const int t = threadIdx.x;
    const int b = blockIdx.x;
    cnt[t] = 0;
    __syncthreads();
    const int lo = boff[b], hi = boff[b + 1];
    for (int i = lo + t; i < hi; i += 512)
        atomicAdd(&cnt[bucketed[i].y & (BRANGE - 1)], 1);
    __syncthreads();
    int node = (b << BSHIFT) + t;
    if (node < M) deg[node] = cnt[t];
}

// one block per bucket: LDS cursors seeded from offs, plain csr stores.
// csr writes stay within the bucket's ~32KB window -> L2-resident, fully combined.
__global__ __launch_bounds__(512) void bucket_fill_kernel(
    const int2* __restrict__ bucketed, const int* __restrict__ boff,
    const int* __restrict__ offs, int* __restrict__ csr, int M)
{
    __shared__ int cur[BRANGE];
    const int t = threadIdx.x;
    const int b = blockIdx.x;
    int node = (b << BSHIFT) + t;
    cur[t] = (node < M) ? offs[node] : 0;
    __syncthreads();
    const int lo = boff[b], hi = boff[b + 1];
    for (int i = lo + t; i < hi; i += 512) {
        int2 e = bucketed[i];
        int p = atomicAdd(&cur[e.y & (BRANGE - 1)], 1);
        csr[p] = e.x;
    }
}

// ---------- fallback-path CSR build (atomic histogram + ranged fill) ----------
__global__ void hist_kernel(const int* __restrict__ dst, int* __restrict__ deg, int ne) {
    int e = blockIdx.x * blockDim.x + threadIdx.x;
    if (e < ne) atomicAdd(&deg[dst[e]], 1);
}

// coalesced 3-stage scan (98 blocks x 1024)
__global__ __launch_bounds__(1024) void scan_local_kernel(
    const int* __restrict__ deg, int* __restrict__ offs, int* __restrict__ bsum, int n)
{
    __shared__ int sh[1024];
    int t = threadIdx.x;
    int i = blockIdx.x * 1024 + t;
    int v = (i < n) ? deg[i] : 0;
    sh[t] = v;
    __syncthreads();
    int acc = v;
    for (int off = 1; off < 1024; off <<= 1) {
        int y = (t >= off) ? sh[t - off] : 0;
        __syncthreads();
        acc += y;
        sh[t] = acc;
        __syncthreads();
    }
    if (i < n) offs[i] = acc - v;  // exclusive within block
    if (t == 1023) bsum[blockIdx.x] = acc;
}

__global__ __launch_bounds__(128) void scan_totals_kernel(
    int* __restrict__ bsum, int* __restrict__ offs, int nb, int n)
{
    __shared__ int sh[128];
    int t = threadIdx.x;
    int v = (t < nb) ? bsum[t] : 0;
    sh[t] = v;
    __syncthreads();
    int acc = v;
    for (int off = 1; off < 128; off <<= 1) {
        int y = (t >= off) ? sh[t - off] : 0;
        __syncthreads();
        acc += y;
        sh[t] = acc;
        __syncthreads();
    }
    if (t < nb) bsum[t] = acc - v;   // exclusive block offsets, in place
    if (t == 127) offs[n] = acc;     // grand total == NE
}

// cursor may be null (bucketed fill path does not need it)
__global__ __launch_bounds__(1024) void scan_finalize_kernel(
    int* __restrict__ offs, const int* __restrict__ bsum, int* __restrict__ cursor, int n)
{
    int i = blockIdx.x * 1024 + threadIdx.x;
    if (i < n) {
        int o = offs[i] + bsum[i >> 10];
        offs[i] = o;
        if (cursor) cursor[i] = o;
    }
}

// fallback (low workspace): atomic-cursor ranged fill
__global__ __launch_bounds__(256) void fill_csr_ranged_kernel(
    const int* __restrict__ src, const int* __restrict__ dst,
    int* __restrict__ cursor, int* __restrict__ csr, int ne, int rangeSize)
{
    const int r = blockIdx.x & 7;
    const int cb = blockIdx.x >> 3;
    const int nchunk = gridDim.x >> 3;
    const unsigned lo = (unsigned)(r * rangeSize);
    for (int e = cb * 256 + threadIdx.x; e < ne; e += nchunk * 256) {
        int d = dst[e];
        int s = src[e];
        if ((unsigned)(d - lo) < (unsigned)rangeSize) {
            int pos = atomicAdd(&cursor[d], 1);
            csr[pos] = s;
        }
    }
}

// ---------- gather: one wave per node, 8-deep masked unroll, bf16 out ----------
template<bool BF16SRC>
__global__ __launch_bounds__(256) void gather_kernel(
    const void* __restrict__ xsrc, const int* __restrict__ offs,
    const int* __restrict__ csr, unsigned short* __restrict__ gb, int M)
{
    const int wave = threadIdx.x >> 6;
    const int lane = threadIdx.x & 63;
    const int node = blockIdx.x * 4 + wave;
    if (node >= M) return;
    const int e0 = offs[node];
    const int e1 = offs[node + 1];

    float s0 = 0.f, s1 = 0.f, t0 = 0.f, t1 = 0.f;
    for (int e = e0; e < e1; e += 8) {
        int id[8];
        float m[8];
#pragma unroll
        for (int j = 0; j < 8; ++j) {
            int ee = e + j;
            bool ok = ee < e1;
            id[j] = csr[ok ? ee : e1 - 1];
            m[j] = ok ? 1.f : 0.f;
        }
#pragma unroll
        for (int j = 0; j < 8; ++j) {
            float lo, hi;
            if (BF16SRC) {
                unsigned v = *(const unsigned*)((const unsigned short*)xsrc +
                                                (size_t)id[j] * 128 + lane * 2);
                lo = bf2f((unsigned short)(v & 0xffffu));
                hi = bf2f((unsigned short)(v >> 16));
            } else {
                float2 v = *(const float2*)((const float*)xsrc +
                                            (size_t)id[j] * 128 + lane * 2);
                lo = v.x;
                hi = v.y;
            }
            if (j & 1) { t0 += m[j] * lo; t1 += m[j] * hi; }
            else       { s0 += m[j] * lo; s1 += m[j] * hi; }
        }
    }
    unsigned pk = (unsigned)f2bf(s0 + t0) | ((unsigned)f2bf(s1 + t1) << 16);
    *(unsigned*)(gb + (size_t)node * 128 + lane * 2) = pk;
}

// ---------- 3-panel bf16 MFMA GEMM + fp32 epilogue ----------
// P1 = x*W1^T ; P2 = g*W2^T ; P34 = g*(W3+W4)^T
// out = sigmoid(2*(P34 + d*(b3+b4))) * (2*(P2 + d*b2)) + P1 + b1
template<bool XBF16>
__global__ __launch_bounds__(256) void gemm_kernel(
    const void* __restrict__ xsrc, const unsigned short* __restrict__ gb,
    const int* __restrict__ deg, const unsigned short* __restrict__ Wb,
    const float* __restrict__ B1, const float* __restrict__ B2,
    const float* __restrict__ B3, const float* __restrict__ B4,
    float* __restrict__ out, int M)
{
    __shared__ unsigned short x_lds[64 * 136];
    __shared__ unsigned short g_lds[64 * 136];

    const int t = threadIdx.x;
    const int wave = t >> 6;
    const int lane = t & 63;
    const int ln = lane & 15;
    const int quad = lane >> 4;
    const int row0 = blockIdx.x * 64;

    // ---- stage x tile ----
    if (XBF16) {
        const unsigned short* xb = (const unsigned short*)xsrc;
#pragma unroll
        for (int i = 0; i < 4; ++i) {
            int c = i * 256 + t;          // 1024 chunks of 16B
            int row = c >> 4;
            int koff = (c & 15) * 8;
            int grow = row0 + row;
            if (grow > M - 1) grow = M - 1;
            *(uint4*)&x_lds[row * 136 + koff] =
                *(const uint4*)(xb + (size_t)grow * 128 + koff);
        }
    } else {
        const float* xf = (const float*)xsrc;
#pragma unroll
        for (int i = 0; i < 8; ++i) {
            int c = i * 256 + t;          // 2048 chunks of float4
            int row = c >> 5;
            int koff = (c & 31) * 4;
            int grow = row0 + row;
            if (grow > M - 1) grow = M - 1;
            float4 v = *(const float4*)(xf + (size_t)grow * 128 + koff);
            unsigned p0 = (unsigned)f2bf(v.x) | ((unsigned)f2bf(v.y) << 16);
            unsigned p1 = (unsigned)f2bf(v.z) | ((unsigned)f2bf(v.w) << 16);
            *(unsigned*)&x_lds[row * 136 + koff]     = p0;
            *(unsigned*)&x_lds[row * 136 + koff + 2] = p1;
        }
    }
    // ---- stage g tile ----
#pragma unroll
    for (int i = 0; i < 4; ++i) {
        int c = i * 256 + t;
        int row = c >> 4;
        int koff = (c & 15) * 8;
        int grow = row0 + row;
        if (grow > M - 1) grow = M - 1;
        *(uint4*)&g_lds[row * 136 + koff] =
            *(const uint4*)(gb + (size_t)grow * 128 + koff);
    }
    __syncthreads();

    // ---- 3-panel GEMM: wave owns cols [wave*32, wave*32+32) ----
    f32x4 acc[3][4][2];
#pragma unroll
    for (int p = 0; p < 3; ++p)
#pragma unroll
        for (int rt = 0; rt < 4; ++rt)
#pragma unroll
            for (int c = 0; c < 2; ++c) {
                acc[p][rt][c][0] = 0.f; acc[p][rt][c][1] = 0.f;
                acc[p][rt][c][2] = 0.f; acc[p][rt][c][3] = 0.f;
            }

#pragma unroll
    for (int kk = 0; kk < 4; ++kk) {
        bf16x8 ax[4], ag[4];
#pragma unroll
        for (int rt = 0; rt < 4; ++rt) {
            ax[rt] = *(const bf16x8*)&x_lds[(rt * 16 + ln) * 136 + kk * 32 + quad * 8];
            ag[rt] = *(const bf16x8*)&g_lds[(rt * 16 + ln) * 136 + kk * 32 + quad * 8];
        }
#pragma unroll
        for (int p = 0; p < 3; ++p) {
#pragma unroll
            for (int c = 0; c < 2; ++c) {
                int col = wave * 32 + c * 16 + ln;
                bf16x8 bw = *(const bf16x8*)(Wb + (size_t)p * 16384 +
                                             (size_t)col * 128 + kk * 32 + quad * 8);
#pragma unroll
                for (int rt = 0; rt < 4; ++rt) {
                    acc[p][rt][c] = __builtin_amdgcn_mfma_f32_16x16x32_bf16(
                        (p == 0) ? ax[rt] : ag[rt], bw, acc[p][rt][c], 0, 0, 0);
                }
            }
        }
    }

    // ---- epilogue (fp32) ----
#pragma unroll
    for (int rt = 0; rt < 4; ++rt) {
#pragma unroll
        for (int i = 0; i < 4; ++i) {
            int row = row0 + rt * 16 + quad * 4 + i;
            if (row < M) {
                float dg = (float)deg[row];
#pragma unroll
                for (int c = 0; c < 2; ++c) {
                    int col = wave * 32 + c * 16 + ln;
                    float p1 = acc[0][rt][c][i] + B1[col];
                    float h2 = 2.f * (acc[1][rt][c][i] + dg * B2[col]);
                    float z  = 2.f * (acc[2][rt][c][i] + dg * (B3[col] + B4[col]));
                    float g = 1.f / (1.f + __expf(-z));
                    out[(size_t)row * 128 + col] = g * h2 + p1;
                }
            }
        }
    }
}

extern "C" void kernel_launch(void* const* d_in, const int* in_sizes, int n_in,
                              void* d_out, int out_size, void* d_ws, size_t ws_size,
                              hipStream_t stream) {
    const float* x  = (const float*)d_in[0];
    const int* eidx = (const int*)d_in[1];
    const float* W1 = (const float*)d_in[2];
    const float* B1 = (const float*)d_in[3];
    const float* W2 = (const float*)d_in[4];
    const float* B2 = (const float*)d_in[5];
    const float* W3 = (const float*)d_in[6];
    const float* B3 = (const float*)d_in[7];
    const float* W4 = (const float*)d_in[8];
    const float* B4 = (const float*)d_in[9];
    float* out      = (float*)d_out;

    const int M  = in_sizes[0] / 128;   // 100000 nodes
    const int NE = in_sizes[1] / 2;     // 1600000 edges
    const int* src = eidx;
    const int* dst = eidx + NE;

    const int NB = (M + BRANGE - 1) >> BSHIFT;   // buckets (196 for M=100000)

    auto pad = [](size_t b) { return (b + 127) & ~(size_t)127; };
    const size_t xb_bytes  = pad((size_t)M * 128 * 2);
    const size_t gb_bytes  = pad((size_t)M * 128 * 2);
    const size_t wb_bytes  = pad((size_t)3 * 16384 * 2);
    const size_t deg_bytes = pad((size_t)M * 4);
    const size_t off_bytes = pad((size_t)(M + 1) * 4);
    const size_t csr_bytes = pad((size_t)NE * 4);
    const size_t bkt_bytes = pad((size_t)NE * 8);

    const size_t need_full = xb_bytes + gb_bytes + wb_bytes + deg_bytes + off_bytes +
                             1024 + csr_bytes + bkt_bytes + 4 * 1024;
    const bool full = (NB <= 256) && ws_size >= need_full + 1024;

    char* ws = (char*)d_ws;
    size_t off = 0;
    auto take = [&](size_t bytes) -> char* {
        char* p = ws + off;
        off = (off + bytes + 127) & ~(size_t)127;
        return p;
    };

    const int nbScan = (M + 1023) / 1024;

    if (full) {
        unsigned short* xb = (unsigned short*)take(xb_bytes);
        unsigned short* gb = (unsigned short*)take(gb_bytes);
        unsigned short* Wb = (unsigned short*)take(wb_bytes);
        int* deg   = (int*)take((size_t)M * 4);
        int* offs  = (int*)take((size_t)(M + 1) * 4);
        int* bsum  = (int*)take(256 * 4);
        int* csr   = (int*)take((size_t)NE * 4);
        int2* bkt  = (int2*)take((size_t)NE * 8);
        int* bcnt  = (int*)take(256 * 4);
        int* boff  = (int*)take(257 * 4);
        int* gcur  = (int*)take(256 * 4);

        const int nx4 = M * 128 / 4;
        const int chunk = (NE + 255) / 256;

        prep_kernel<<<(M * 32 + 255) / 256, 256, 0, stream>>>(
            x, W1, W2, W3, W4, xb, Wb, deg, bcnt, M, nx4);
        bucket_hist_kernel<<<256, 512, 0, stream>>>(dst, bcnt, NE, NB);
        bucket_scan_kernel<<<1, 256, 0, stream>>>(bcnt, boff, gcur, NB);
        bucketize_kernel<<<256, 512, 0, stream>>>(src, dst, gcur, bkt, NE, chunk);
        bucket_count_kernel<<<NB, 512, 0, stream>>>(bkt, boff, deg, M);
        scan_local_kernel<<<nbScan, 1024, 0, stream>>>(deg, offs, bsum, M);
        scan_totals_kernel<<<1, 128, 0, stream>>>(bsum, offs, nbScan, M);
        scan_finalize_kernel<<<nbScan, 1024, 0, stream>>>(offs, bsum, nullptr, M);
        bucket_fill_kernel<<<NB, 512, 0, stream>>>(bkt, boff, offs, csr, M);
        gather_kernel<true><<<(M + 3) / 4, 256, 0, stream>>>(xb, offs, csr, gb, M);
        gemm_kernel<true><<<(M + 63) / 64, 256, 0, stream>>>(
            xb, gb, deg, Wb, B1, B2, B3, B4, out, M);
    } else {
        // low-workspace fallback: fp32 gather + atomic hist + atomic-cursor ranged fill
        unsigned short* gb = (unsigned short*)take(gb_bytes);
        unsigned short* Wb = (unsigned short*)take(wb_bytes);
        int* deg    = (int*)take((size_t)M * 4);
        int* offs   = (int*)take((size_t)(M + 1) * 4);
        int* cursor = (int*)take((size_t)M * 4);
        int* bsum   = (int*)take(256 * 4);
        int* csr    = (int*)take((size_t)NE * 4);

        const int prep_elems = (M > 16384 ? M : 16384);
        const int rangeSize = (M + 7) / 8;
        prep_kernel<<<(prep_elems + 255) / 256, 256, 0, stream>>>(
            x, W1, W2, W3, W4, gb, Wb, deg, nullptr, M, 0);
        hist_kernel<<<(NE + 255) / 256, 256, 0, stream>>>(dst, deg, NE);
        scan_local_kernel<<<nbScan, 1024, 0, stream>>>(deg, offs, bsum, M);
        scan_totals_kernel<<<1, 128, 0, stream>>>(bsum, offs, nbScan, M);
        scan_finalize_kernel<<<nbScan, 1024, 0, stream>>>(offs, bsum, cursor, M);
        fill_csr_ranged_kernel<<<2048, 256, 0, stream>>>(src, dst, cursor, csr, NE, rangeSize);
        gather_kernel<false><<<(M + 3) / 4, 256, 0, stream>>>(x, offs, csr, gb, M);
        gemm_kernel<false><<<(M + 63) / 64, 256, 0, stream>>>(
            x, gb, deg, Wb, B1, B2, B3, B4, out, M);
    }
}